// Round 2
// baseline (1435.567 us; speedup 1.0000x reference)
//
#include <hip/hip_runtime.h>
#include <math.h>

#define KK 10
#define NN 96
#define TT 40
#define HID 48
#define NBIN 36

#define HZf 10.0f
#define R0f 0.5f
#define R1f 4.0f
#define RSTEPf ((4.0f - 0.5f) / 6.0f)
#define TWO_PIf 6.2831853071795864769f
#define TSTEPf (6.2831853071795864769f / 6.0f)

__device__ __forceinline__ float sigmoidf_(float x) { return 1.0f / (1.0f + expf(-x)); }

// ---------- device-scope barrier for phase1 (96 co-resident blocks) ----------
__device__ __forceinline__ void gbar(unsigned* counter, unsigned* gen, unsigned nb) {
    __syncthreads();
    if (threadIdx.x == 0) {
        unsigned g = __hip_atomic_load(gen, __ATOMIC_RELAXED, __HIP_MEMORY_SCOPE_AGENT);
        unsigned a = __hip_atomic_fetch_add(counter, 1u, __ATOMIC_ACQ_REL, __HIP_MEMORY_SCOPE_AGENT);
        if (a == nb - 1u) {
            __hip_atomic_store(counter, 0u, __ATOMIC_RELAXED, __HIP_MEMORY_SCOPE_AGENT);
            __hip_atomic_store(gen, g + 1u, __ATOMIC_RELEASE, __HIP_MEMORY_SCOPE_AGENT);
        } else {
            unsigned cur;
            do {
                __builtin_amdgcn_s_sleep(1);
                cur = __hip_atomic_load(gen, __ATOMIC_RELAXED, __HIP_MEMORY_SCOPE_AGENT);
            } while (cur == g);
            (void)__hip_atomic_load(gen, __ATOMIC_ACQUIRE, __HIP_MEMORY_SCOPE_AGENT);
        }
    }
    __syncthreads();
}

// ---------- conv1: (4,160,160) -> relu -> (16,80,80), stride 2, pad 2 ----------
__global__ void conv1_k(const float* __restrict__ img, const float* __restrict__ w,
                        const float* __restrict__ b, float* __restrict__ out) {
    int idx = blockIdx.x * blockDim.x + threadIdx.x;
    if (idx >= 16 * 80 * 80) return;
    int x = idx % 80, y = (idx / 80) % 80, o = idx / 6400;
    float acc = b[o];
    for (int c = 0; c < 4; c++) {
        for (int ky = 0; ky < 5; ky++) {
            int iy = y * 2 + ky - 2;
            if (iy < 0 || iy >= 160) continue;
            for (int kx = 0; kx < 5; kx++) {
                int ix = x * 2 + kx - 2;
                if (ix < 0 || ix >= 160) continue;
                acc += img[(c * 160 + iy) * 160 + ix] * w[((o * 4 + c) * 5 + ky) * 5 + kx];
            }
        }
    }
    out[idx] = fmaxf(acc, 0.0f);
}

// ---------- conv2: (16,80,80) -> relu -> (32,80,80), stride 1, pad 2 ----------
__global__ void conv2_k(const float* __restrict__ in, const float* __restrict__ w,
                        const float* __restrict__ b, float* __restrict__ out) {
    int idx = blockIdx.x * blockDim.x + threadIdx.x;
    if (idx >= 32 * 80 * 80) return;
    int x = idx % 80, y = (idx / 80) % 80, o = idx / 6400;
    float acc = b[o];
    for (int c = 0; c < 16; c++) {
        for (int ky = 0; ky < 5; ky++) {
            int iy = y + ky - 2;
            if (iy < 0 || iy >= 80) continue;
            for (int kx = 0; kx < 5; kx++) {
                int ix = x + kx - 2;
                if (ix < 0 || ix >= 80) continue;
                acc += in[(c * 80 + iy) * 80 + ix] * w[((o * 16 + c) * 5 + ky) * 5 + kx];
            }
        }
    }
    out[idx] = fmaxf(acc, 0.0f);
}

// ---------- weight transposes ----------
__global__ void prep_w(const float* __restrict__ scf, const float* __restrict__ wih,
                       const float* __restrict__ whh, float* __restrict__ wt_scf,
                       float* __restrict__ wih_lt, float* __restrict__ wih_rt,
                       float* __restrict__ whh_t) {
    int idx = blockIdx.x * blockDim.x + threadIdx.x;
    if (idx < 36 * 48 * 48) {
        int o = idx % 48, d = (idx / 48) % 48, b = idx / 2304;
        wt_scf[idx] = scf[o * 1728 + b * 48 + d];
    }
    int idx2 = idx - 36 * 48 * 48;
    if (idx2 >= 0 && idx2 < 48 * 144) {
        int g = idx2 % 144, d = idx2 / 144;
        wih_lt[idx2] = wih[g * 96 + d];
        wih_rt[idx2] = wih[g * 96 + 48 + d];
        whh_t[idx2] = whh[g * 48 + d];
    }
}

// ---------- lhalf[t][row][48] = [feat(32) | relu(vel@fcvel)(16)] ----------
__global__ void lhalf_k(const float* __restrict__ yp, const float* __restrict__ cur,
                        const float* __restrict__ fmap, const float* __restrict__ vw,
                        const float* __restrict__ vb, float* __restrict__ lhalf) {
    int item = blockIdx.x;  // t*K*N + k*N + n
    int n = item % NN, k = (item / NN) % KK, t = item / (KK * NN);
    int lane = threadIdx.x;
    float lx = yp[((k * TT + t) * NN + n) * 2 + 0];
    float ly = yp[((k * TT + t) * NN + n) * 2 + 1];
    float px, py;
    if (t == 0) { px = cur[n * 2]; py = cur[n * 2 + 1]; }
    else { px = yp[((k * TT + t - 1) * NN + n) * 2]; py = yp[((k * TT + t - 1) * NN + n) * 2 + 1]; }
    float vx = (lx - px) * HZf, vy = (ly - py) * HZf;
    int ui = 40 - (int)ly;
    int vi = 40 - (int)lx;
    ui = min(max(ui, 0), 79);
    vi = min(max(vi, 0), 79);
    int row = k * NN + n;
    float* dst = lhalf + ((size_t)t * KK * NN + row) * 48;
    if (lane < 32) {
        dst[lane] = fmap[(lane * 80 + ui) * 80 + vi];
    } else if (lane < 48) {
        int f = lane - 32;
        float a = vb[f] + vx * vw[f * 2 + 0] + vy * vw[f * 2 + 1];
        dst[lane] = fmaxf(a, 0.0f);
    }
}

// ---------- bins: one block per (t,k), shared-atomic winner/count ----------
__global__ __launch_bounds__(256) void bins2_k(const float* __restrict__ yp,
                                               signed char* __restrict__ win,
                                               unsigned char* __restrict__ cnt) {
    int tk = blockIdx.x;  // t*10 + k
    int k = tk % KK, t = tk / KK;
    int tid = threadIdx.x;
    __shared__ float xs[96], ys[96];
    __shared__ int win_s[96 * 36];
    __shared__ int cnt_s[96 * 36];
    if (tid < 96) {
        xs[tid] = yp[((k * TT + t) * NN + tid) * 2 + 0];
        ys[tid] = yp[((k * TT + t) * NN + tid) * 2 + 1];
    }
    for (int i = tid; i < 96 * 36; i += 256) { win_s[i] = -1; cnt_s[i] = 0; }
    __syncthreads();
    for (int p = tid; p < 96 * 96; p += 256) {
        int i = p / 96, j = p % 96;
        if (i == j) continue;
        float dx = xs[j] - xs[i], dy = ys[j] - ys[i];
        float dist = sqrtf(dx * dx + dy * dy);
        if (dist < R0f || dist > R1f) continue;
        float dsafe = fmaxf(dist, 1e-10f);
        float cost = fminf(fmaxf(dx / dsafe, -1.0f), 1.0f);
        float ac = acosf(cost);
        float theta = (dy < 0.0f) ? (TWO_PIf - ac) : ac;
        int ub = (int)((dist - R0f) / RSTEPf); ub = min(max(ub, 0), 5);
        int vb = (int)(theta / TSTEPf);        vb = min(max(vb, 0), 5);
        int b = ub * 6 + vb;
        atomicAdd(&cnt_s[i * 36 + b], 1);
        atomicMax(&win_s[i * 36 + b], j);
    }
    __syncthreads();
    size_t base = (size_t)tk * 96 * 36;
    for (int i = tid; i < 96 * 36; i += 256) {
        win[base + i] = (signed char)win_s[i];
        cnt[base + i] = (unsigned char)cnt_s[i];
    }
}

// ---------- phase 1: k=0 chain (96 rows), persistent, barrier per step ----------
__global__ __launch_bounds__(64) void phase1_k(
    const float* __restrict__ hx, float* __restrict__ h0hist,
    const float* __restrict__ lhalf, const signed char* __restrict__ win,
    const unsigned char* __restrict__ cnt, const float* __restrict__ wt_scf,
    const float* __restrict__ wih_lt, const float* __restrict__ wih_rt,
    const float* __restrict__ whh_t, const float* __restrict__ bih,
    const float* __restrict__ bhh, const float* __restrict__ scfb,
    const float* __restrict__ scw, float* __restrict__ score_acc,
    float* __restrict__ hfin, unsigned* __restrict__ bar) {
    const int r = blockIdx.x;      // 0..95
    const int lane = threadIdx.x;  // 0..63
    const int lo = lane < 48 ? lane : 47;
    unsigned* cbar = bar;
    unsigned* genb = bar + 1;
    if (lane < 48) h0hist[r * 48 + lane] = hx[r * 48 + lane];
    gbar(cbar, genb, 96);
    const float sw = (lane < 48) ? scw[lane] : 0.0f;
    const float b0 = bih[lo], b1 = bih[48 + lo], b2 = bih[96 + lo];
    const float c0 = bhh[lo], c1 = bhh[48 + lo], c2 = bhh[96 + lo];
    const float sb = scfb[lo];
    float score = 0.0f;
    float hn = 0.0f;
    for (int t = 0; t < TT; ++t) {
        const float* hcur = h0hist + t * 4608;
        const float hreg = hcur[r * 48 + lo];
        const int* wrI = (const int*)(win + ((size_t)t * 960 + r) * 36);
        const int* crI = (const int*)(cnt + ((size_t)t * 960 + r) * 36);
        int wv[9], cv[9];
#pragma unroll
        for (int q = 0; q < 9; ++q) { wv[q] = wrI[q]; cv[q] = crI[q]; }
        float acc = sb;
        for (int b = 0; b < 36; ++b) {
            int w = (int)(signed char)((wv[b >> 2] >> ((b & 3) * 8)) & 0xff);
            if (w < 0) continue;
            int c = (cv[b >> 2] >> ((b & 3) * 8)) & 0xff;
            float hv = hcur[w * 48 + lo];
            const float* wb = wt_scf + b * 2304;
            float part = 0.0f;
#pragma unroll 8
            for (int d = 0; d < 48; ++d) part += __shfl(hv, d) * wb[d * 48 + lo];
            acc += part * (1.0f / (float)c);
        }
        float rh = fmaxf(acc, 0.0f);
        const float* lh = lhalf + ((size_t)t * 960 + r) * 48;
        float lreg = lh[lo];
        float gi0 = b0, gi1 = b1, gi2 = b2, gh0 = c0, gh1 = c1, gh2 = c2;
#pragma unroll 4
        for (int d = 0; d < 48; ++d) {
            float lhd = __shfl(lreg, d), rhd = __shfl(rh, d), hd = __shfl(hreg, d);
            const float* lt = wih_lt + d * 144;
            const float* rt = wih_rt + d * 144;
            const float* ht = whh_t + d * 144;
            gi0 += lhd * lt[lo] + rhd * rt[lo];
            gi1 += lhd * lt[48 + lo] + rhd * rt[48 + lo];
            gi2 += lhd * lt[96 + lo] + rhd * rt[96 + lo];
            gh0 += hd * ht[lo];
            gh1 += hd * ht[48 + lo];
            gh2 += hd * ht[96 + lo];
        }
        float rr = sigmoidf_(gi0 + gh0);
        float zz = sigmoidf_(gi1 + gh1);
        float ng = tanhf(gi2 + rr * gh2);
        hn = (1.0f - zz) * ng + zz * hreg;
        if (lane < 48) h0hist[(t + 1) * 4608 + r * 48 + lane] = hn;
        score += hn * sw;
        gbar(cbar, genb, 96);
    }
    if (lane < 48) hfin[r * 48 + lane] = hn;
    for (int off = 32; off; off >>= 1) score += __shfl_down(score, off);
    if (lane == 0) score_acc[r] = score;
}

// ---------- phase 2: rows 96..959, independent 40-step recurrences ----------
__global__ __launch_bounds__(64) void phase2_k(
    const float* __restrict__ hx, const float* __restrict__ h0hist,
    const float* __restrict__ lhalf, const signed char* __restrict__ win,
    const unsigned char* __restrict__ cnt, const float* __restrict__ wt_scf,
    const float* __restrict__ wih_lt, const float* __restrict__ wih_rt,
    const float* __restrict__ whh_t, const float* __restrict__ bih,
    const float* __restrict__ bhh, const float* __restrict__ scfb,
    const float* __restrict__ scw, float* __restrict__ score_acc,
    float* __restrict__ hfin) {
    const int r = 96 + blockIdx.x;  // 96..959
    const int lane = threadIdx.x;
    const int lo = lane < 48 ? lane : 47;
    const float sw = (lane < 48) ? scw[lane] : 0.0f;
    const float b0 = bih[lo], b1 = bih[48 + lo], b2 = bih[96 + lo];
    const float c0 = bhh[lo], c1 = bhh[48 + lo], c2 = bhh[96 + lo];
    const float sb = scfb[lo];
    float hreg = hx[(r % 96) * 48 + lo];
    float score = 0.0f;
    for (int t = 0; t < TT; ++t) {
        const float* hcur = h0hist + t * 4608;
        const int* wrI = (const int*)(win + ((size_t)t * 960 + r) * 36);
        const int* crI = (const int*)(cnt + ((size_t)t * 960 + r) * 36);
        int wv[9], cv[9];
#pragma unroll
        for (int q = 0; q < 9; ++q) { wv[q] = wrI[q]; cv[q] = crI[q]; }
        float acc = sb;
        for (int b = 0; b < 36; ++b) {
            int w = (int)(signed char)((wv[b >> 2] >> ((b & 3) * 8)) & 0xff);
            if (w < 0) continue;
            int c = (cv[b >> 2] >> ((b & 3) * 8)) & 0xff;
            float hv = hcur[w * 48 + lo];
            const float* wb = wt_scf + b * 2304;
            float part = 0.0f;
#pragma unroll 8
            for (int d = 0; d < 48; ++d) part += __shfl(hv, d) * wb[d * 48 + lo];
            acc += part * (1.0f / (float)c);
        }
        float rh = fmaxf(acc, 0.0f);
        const float* lh = lhalf + ((size_t)t * 960 + r) * 48;
        float lreg = lh[lo];
        float gi0 = b0, gi1 = b1, gi2 = b2, gh0 = c0, gh1 = c1, gh2 = c2;
#pragma unroll 4
        for (int d = 0; d < 48; ++d) {
            float lhd = __shfl(lreg, d), rhd = __shfl(rh, d), hd = __shfl(hreg, d);
            const float* lt = wih_lt + d * 144;
            const float* rt = wih_rt + d * 144;
            const float* ht = whh_t + d * 144;
            gi0 += lhd * lt[lo] + rhd * rt[lo];
            gi1 += lhd * lt[48 + lo] + rhd * rt[48 + lo];
            gi2 += lhd * lt[96 + lo] + rhd * rt[96 + lo];
            gh0 += hd * ht[lo];
            gh1 += hd * ht[48 + lo];
            gh2 += hd * ht[96 + lo];
        }
        float rr = sigmoidf_(gi0 + gh0);
        float zz = sigmoidf_(gi1 + gh1);
        float ng = tanhf(gi2 + rr * gh2);
        float hn = (1.0f - zz) * ng + zz * hreg;
        hreg = hn;
        score += hn * sw;
    }
    if (lane < 48) hfin[r * 48 + lane] = hreg;
    for (int off = 32; off; off >>= 1) score += __shfl_down(score, off);
    if (lane == 0) score_acc[r] = score;
}

// ---------- epilogue: delta_y + score ----------
__global__ void final_k(const float* __restrict__ hlast, const float* __restrict__ score_acc,
                        const float* __restrict__ dyw, const float* __restrict__ dyb,
                        const float* __restrict__ scoreb, float* __restrict__ out) {
    int row = blockIdx.x, lane = threadIdx.x;
    int n = row % 96, k = row / 96;
    __shared__ float sh_h[48];
    if (lane < 48) sh_h[lane] = hlast[row * 48 + lane];
    __syncthreads();
    if (lane < 80) {
        float a = dyb[lane];
#pragma unroll 8
        for (int d = 0; d < 48; d++) a += sh_h[d] * dyw[lane * 48 + d];
        a = fmaxf(a, 0.0f);
        int j = lane / 40, tt = lane % 40;
        out[((k * TT + tt) * NN + n) * 2 + j] = a;
    } else if (lane == 80) {
        out[76800 + row] = score_acc[row] + 40.0f * scoreb[0];
    }
}

extern "C" void kernel_launch(void* const* d_in, const int* in_sizes, int n_in,
                              void* d_out, int out_size, void* d_ws, size_t ws_size,
                              hipStream_t stream) {
    const float* hx  = (const float*)d_in[0];
    const float* cur = (const float*)d_in[1];
    const float* yp  = (const float*)d_in[2];
    const float* img = (const float*)d_in[3];
    const float* c1w = (const float*)d_in[4];
    const float* c1b = (const float*)d_in[5];
    const float* c2w = (const float*)d_in[6];
    const float* c2b = (const float*)d_in[7];
    const float* vw  = (const float*)d_in[8];
    const float* vb  = (const float*)d_in[9];
    const float* wih = (const float*)d_in[10];
    const float* whh = (const float*)d_in[11];
    const float* bih = (const float*)d_in[12];
    const float* bhh = (const float*)d_in[13];
    const float* scfw = (const float*)d_in[14];
    const float* scfb = (const float*)d_in[15];
    const float* scw  = (const float*)d_in[16];
    const float* scb  = (const float*)d_in[17];
    const float* dyw  = (const float*)d_in[18];
    const float* dyb  = (const float*)d_in[19];
    float* out = (float*)d_out;

    char* ws = (char*)d_ws;
    // lifetimes: fmap1/fmap dead after lhalf_k; h0hist (written in phase1) aliases them.
    float* fmap1 = (float*)(ws + 0);               // 409600 B   [dead after conv2]
    float* h0hist = (float*)(ws + 0);              // 755712 B   [phase1+]
    float* fmap  = (float*)(ws + 819200);          // 819200 B   [dead after lhalf]
    float* lhalf = (float*)(ws + 1638400);         // 7372800 B  -> 9011200
    signed char* win = (signed char*)(ws + 9011200);     // 1382400 -> 10393600
    unsigned char* cnt = (unsigned char*)(ws + 10393600);// 1382400 -> 11776000
    float* hfin = (float*)(ws + 11776000);         // 184320 -> 11960320
    float* score_acc = (float*)(ws + 11960320);    // 3840 -> 11964160
    float* wt_scf = (float*)(ws + 11964160);       // 331776 -> 12295936... (see note)
    // NOTE: keep total under the 12.15MB proven in round 0: move weight bufs earlier
    // Actually place them within the proven range:
    wt_scf = (float*)(ws + 11964160);              // 331776 B, ends 12295936
    float* wih_lt = (float*)(ws + 12295936);       // 27648, ends 12323584
    float* wih_rt = (float*)(ws + 12323584);       // 27648, ends 12351232
    float* whh_t  = (float*)(ws + 12351232);       // 27648, ends 12378880
    unsigned* bar = (unsigned*)(ws + 12378880);    // 8 B,  ends 12378888

    hipMemsetAsync(bar, 0, 8, stream);

    conv1_k<<<400, 256, 0, stream>>>(img, c1w, c1b, fmap1);
    conv2_k<<<800, 256, 0, stream>>>(fmap1, c2w, c2b, fmap);
    prep_w<<<(36 * 48 * 48 + 48 * 144 + 255) / 256, 256, 0, stream>>>(scfw, wih, whh, wt_scf,
                                                                      wih_lt, wih_rt, whh_t);
    lhalf_k<<<TT * KK * NN, 64, 0, stream>>>(yp, cur, fmap, vw, vb, lhalf);
    bins2_k<<<TT * KK, 256, 0, stream>>>(yp, win, cnt);

    phase1_k<<<96, 64, 0, stream>>>(hx, h0hist, lhalf, win, cnt, wt_scf, wih_lt, wih_rt,
                                    whh_t, bih, bhh, scfb, scw, score_acc, hfin, bar);
    phase2_k<<<864, 64, 0, stream>>>(hx, h0hist, lhalf, win, cnt, wt_scf, wih_lt, wih_rt,
                                     whh_t, bih, bhh, scfb, scw, score_acc, hfin);
    final_k<<<960, 128, 0, stream>>>(hfin, score_acc, dyw, dyb, scb, out);
}

// Round 3
// 1317.657 us; speedup vs baseline: 1.0895x; 1.0895x over previous
//
#include <hip/hip_runtime.h>
#include <math.h>

#define KK 10
#define NN 96
#define TT 40
#define HID 48
#define NBIN 36

#define HZf 10.0f
#define R0f 0.5f
#define R1f 4.0f
#define RSTEPf ((4.0f - 0.5f) / 6.0f)
#define TWO_PIf 6.2831853071795864769f
#define TSTEPf (6.2831853071795864769f / 6.0f)

__device__ __forceinline__ float sigmoidf_(float x) { return 1.0f / (1.0f + expf(-x)); }

// ---------- distributed sense barrier: 96 flags, 128B apart, no RMW ----------
__device__ __forceinline__ void chain_bar(int* flags, int s, int lane, int r) {
    if (lane == 0)
        __hip_atomic_store(&flags[r * 32], s, __ATOMIC_RELEASE, __HIP_MEMORY_SCOPE_AGENT);
    for (;;) {
        int f0 = __hip_atomic_load(&flags[lane * 32], __ATOMIC_RELAXED, __HIP_MEMORY_SCOPE_AGENT);
        int f1 = (lane < 32)
                     ? __hip_atomic_load(&flags[(64 + lane) * 32], __ATOMIC_RELAXED,
                                         __HIP_MEMORY_SCOPE_AGENT)
                     : s;
        if (__all((f0 >= s) && (f1 >= s))) break;
        __builtin_amdgcn_s_sleep(2);
    }
    __threadfence();  // acquire: make remote h stores visible
}

__device__ __forceinline__ void wait_tdone(const int* t_done, int tgt) {
    if (__hip_atomic_load(t_done, __ATOMIC_RELAXED, __HIP_MEMORY_SCOPE_AGENT) < tgt) {
        for (;;) {
            __builtin_amdgcn_s_sleep(8);
            if (__hip_atomic_load(t_done, __ATOMIC_RELAXED, __HIP_MEMORY_SCOPE_AGENT) >= tgt)
                break;
        }
    }
    __threadfence();
}

// ---------- conv1: (4,160,160) -> relu -> (16,80,80), stride 2, pad 2 ----------
__global__ void conv1_k(const float* __restrict__ img, const float* __restrict__ w,
                        const float* __restrict__ b, float* __restrict__ out) {
    int idx = blockIdx.x * blockDim.x + threadIdx.x;
    if (idx >= 16 * 80 * 80) return;
    int x = idx % 80, y = (idx / 80) % 80, o = idx / 6400;
    float acc = b[o];
    for (int c = 0; c < 4; c++) {
        for (int ky = 0; ky < 5; ky++) {
            int iy = y * 2 + ky - 2;
            if (iy < 0 || iy >= 160) continue;
            for (int kx = 0; kx < 5; kx++) {
                int ix = x * 2 + kx - 2;
                if (ix < 0 || ix >= 160) continue;
                acc += img[(c * 160 + iy) * 160 + ix] * w[((o * 4 + c) * 5 + ky) * 5 + kx];
            }
        }
    }
    out[idx] = fmaxf(acc, 0.0f);
}

// ---------- conv2: (16,80,80) -> relu -> (32,80,80), stride 1, pad 2 ----------
__global__ void conv2_k(const float* __restrict__ in, const float* __restrict__ w,
                        const float* __restrict__ b, float* __restrict__ out) {
    int idx = blockIdx.x * blockDim.x + threadIdx.x;
    if (idx >= 32 * 80 * 80) return;
    int x = idx % 80, y = (idx / 80) % 80, o = idx / 6400;
    float acc = b[o];
    for (int c = 0; c < 16; c++) {
        for (int ky = 0; ky < 5; ky++) {
            int iy = y + ky - 2;
            if (iy < 0 || iy >= 80) continue;
            for (int kx = 0; kx < 5; kx++) {
                int ix = x + kx - 2;
                if (ix < 0 || ix >= 80) continue;
                acc += in[(c * 80 + iy) * 80 + ix] * w[((o * 16 + c) * 5 + ky) * 5 + kx];
            }
        }
    }
    out[idx] = fmaxf(acc, 0.0f);
}

// ---------- weight transposes ----------
__global__ void prep_w(const float* __restrict__ scf, const float* __restrict__ wih,
                       const float* __restrict__ whh, float* __restrict__ wt_scf,
                       float* __restrict__ wih_lt, float* __restrict__ wih_rt,
                       float* __restrict__ whh_t) {
    int idx = blockIdx.x * blockDim.x + threadIdx.x;
    if (idx < 36 * 48 * 48) {
        int o = idx % 48, d = (idx / 48) % 48, b = idx / 2304;
        wt_scf[idx] = scf[o * 1728 + b * 48 + d];
    }
    int idx2 = idx - 36 * 48 * 48;
    if (idx2 >= 0 && idx2 < 48 * 144) {
        int g = idx2 % 144, d = idx2 / 144;
        wih_lt[idx2] = wih[g * 96 + d];
        wih_rt[idx2] = wih[g * 96 + 48 + d];
        whh_t[idx2] = whh[g * 48 + d];
    }
}

// ---------- lhalf[t][row][48] = [feat(32) | relu(vel@fcvel)(16)] ----------
__global__ void lhalf_k(const float* __restrict__ yp, const float* __restrict__ cur,
                        const float* __restrict__ fmap, const float* __restrict__ vw,
                        const float* __restrict__ vb, float* __restrict__ lhalf) {
    int item = blockIdx.x;  // t*K*N + k*N + n
    int n = item % NN, k = (item / NN) % KK, t = item / (KK * NN);
    int lane = threadIdx.x;
    float lx = yp[((k * TT + t) * NN + n) * 2 + 0];
    float ly = yp[((k * TT + t) * NN + n) * 2 + 1];
    float px, py;
    if (t == 0) { px = cur[n * 2]; py = cur[n * 2 + 1]; }
    else { px = yp[((k * TT + t - 1) * NN + n) * 2]; py = yp[((k * TT + t - 1) * NN + n) * 2 + 1]; }
    float vx = (lx - px) * HZf, vy = (ly - py) * HZf;
    int ui = 40 - (int)ly;
    int vi = 40 - (int)lx;
    ui = min(max(ui, 0), 79);
    vi = min(max(vi, 0), 79);
    int row = k * NN + n;
    float* dst = lhalf + ((size_t)t * KK * NN + row) * 48;
    if (lane < 32) {
        dst[lane] = fmap[(lane * 80 + ui) * 80 + vi];
    } else if (lane < 48) {
        int f = lane - 32;
        float a = vb[f] + vx * vw[f * 2 + 0] + vy * vw[f * 2 + 1];
        dst[lane] = fmaxf(a, 0.0f);
    }
}

// ---------- bins: one block per (t,k), shared-atomic winner/count ----------
__global__ __launch_bounds__(256) void bins2_k(const float* __restrict__ yp,
                                               signed char* __restrict__ win,
                                               unsigned char* __restrict__ cnt) {
    int tk = blockIdx.x;  // t*10 + k
    int k = tk % KK, t = tk / KK;
    int tid = threadIdx.x;
    __shared__ float xs[96], ys[96];
    __shared__ int win_s[96 * 36];
    __shared__ int cnt_s[96 * 36];
    if (tid < 96) {
        xs[tid] = yp[((k * TT + t) * NN + tid) * 2 + 0];
        ys[tid] = yp[((k * TT + t) * NN + tid) * 2 + 1];
    }
    for (int i = tid; i < 96 * 36; i += 256) { win_s[i] = -1; cnt_s[i] = 0; }
    __syncthreads();
    for (int p = tid; p < 96 * 96; p += 256) {
        int i = p / 96, j = p % 96;
        if (i == j) continue;
        float dx = xs[j] - xs[i], dy = ys[j] - ys[i];
        float dist = sqrtf(dx * dx + dy * dy);
        if (dist < R0f || dist > R1f) continue;
        float dsafe = fmaxf(dist, 1e-10f);
        float cost = fminf(fmaxf(dx / dsafe, -1.0f), 1.0f);
        float ac = acosf(cost);
        float theta = (dy < 0.0f) ? (TWO_PIf - ac) : ac;
        int ub = (int)((dist - R0f) / RSTEPf); ub = min(max(ub, 0), 5);
        int vb = (int)(theta / TSTEPf);        vb = min(max(vb, 0), 5);
        int b = ub * 6 + vb;
        atomicAdd(&cnt_s[i * 36 + b], 1);
        atomicMax(&win_s[i * 36 + b], j);
    }
    __syncthreads();
    size_t base = (size_t)tk * 96 * 36;
    for (int i = tid; i < 96 * 36; i += 256) {
        win[base + i] = (signed char)win_s[i];
        cnt[base + i] = (unsigned char)cnt_s[i];
    }
}

// ---------- merged recurrence: blocks 0..95 = chain (k=0), 96..959 = followers ----------
__global__ __launch_bounds__(64) void recur_k(
    const float* __restrict__ hx, float* __restrict__ h0hist,
    const float* __restrict__ lhalf, const signed char* __restrict__ win,
    const unsigned char* __restrict__ cnt, const float* __restrict__ wt_scf,
    const float* __restrict__ wih_lt, const float* __restrict__ wih_rt,
    const float* __restrict__ whh_t, const float* __restrict__ bih,
    const float* __restrict__ bhh, const float* __restrict__ scfb,
    const float* __restrict__ scw, float* __restrict__ score_acc,
    float* __restrict__ hfin, int* __restrict__ flags, int* __restrict__ t_done) {
    const int r = blockIdx.x;      // 0..959
    const int lane = threadIdx.x;  // 0..63 (one wave per block)
    const int lo = lane < 48 ? lane : 47;
    const bool chain = (r < 96);
    const float sw = (lane < 48) ? scw[lane] : 0.0f;
    const float b0 = bih[lo], b1 = bih[48 + lo], b2 = bih[96 + lo];
    const float c0 = bhh[lo], c1 = bhh[48 + lo], c2 = bhh[96 + lo];
    const float sb = scfb[lo];
    float hreg = hx[(r % 96) * 48 + lo];

    if (chain) {
        if (lane < 48) h0hist[r * 48 + lane] = hreg;
        chain_bar(flags, 1, lane, r);
        if (r == 0 && lane == 0)
            __hip_atomic_store(t_done, 1, __ATOMIC_RELEASE, __HIP_MEMORY_SCOPE_AGENT);
    }

    float score = 0.0f;
    for (int t = 0; t < TT; ++t) {
        if (!chain) wait_tdone(t_done, t + 1);
        const float* hcur = h0hist + t * 4608;
        const int* wrI = (const int*)(win + ((size_t)t * 960 + r) * 36);
        const int* crI = (const int*)(cnt + ((size_t)t * 960 + r) * 36);
        int wv[9], cv[9];
#pragma unroll
        for (int q = 0; q < 9; ++q) { wv[q] = wrI[q]; cv[q] = crI[q]; }
        float acc = sb;
        for (int b = 0; b < 36; ++b) {
            int w = (int)(signed char)((wv[b >> 2] >> ((b & 3) * 8)) & 0xff);
            if (w < 0) continue;
            int c = (cv[b >> 2] >> ((b & 3) * 8)) & 0xff;
            float hv = hcur[w * 48 + lo];
            const float* wb = wt_scf + b * 2304;
            float part = 0.0f;
#pragma unroll 8
            for (int d = 0; d < 48; ++d) part += __shfl(hv, d) * wb[d * 48 + lo];
            acc += part * (1.0f / (float)c);
        }
        float rh = fmaxf(acc, 0.0f);
        const float* lh = lhalf + ((size_t)t * 960 + r) * 48;
        float lreg = lh[lo];
        float gi0 = b0, gi1 = b1, gi2 = b2, gh0 = c0, gh1 = c1, gh2 = c2;
#pragma unroll 4
        for (int d = 0; d < 48; ++d) {
            float lhd = __shfl(lreg, d), rhd = __shfl(rh, d), hd = __shfl(hreg, d);
            const float* lt = wih_lt + d * 144;
            const float* rt = wih_rt + d * 144;
            const float* ht = whh_t + d * 144;
            gi0 += lhd * lt[lo] + rhd * rt[lo];
            gi1 += lhd * lt[48 + lo] + rhd * rt[48 + lo];
            gi2 += lhd * lt[96 + lo] + rhd * rt[96 + lo];
            gh0 += hd * ht[lo];
            gh1 += hd * ht[48 + lo];
            gh2 += hd * ht[96 + lo];
        }
        float rr = sigmoidf_(gi0 + gh0);
        float zz = sigmoidf_(gi1 + gh1);
        float ng = tanhf(gi2 + rr * gh2);
        float hn = (1.0f - zz) * ng + zz * hreg;
        hreg = hn;
        score += hn * sw;
        if (chain) {
            if (lane < 48) h0hist[(t + 1) * 4608 + r * 48 + lane] = hn;
            chain_bar(flags, t + 2, lane, r);
            if (r == 0 && lane == 0)
                __hip_atomic_store(t_done, t + 2, __ATOMIC_RELEASE, __HIP_MEMORY_SCOPE_AGENT);
        }
    }
    if (lane < 48) hfin[r * 48 + lane] = hreg;
    for (int off = 32; off; off >>= 1) score += __shfl_down(score, off);
    if (lane == 0) score_acc[r] = score;
}

// ---------- epilogue: delta_y + score ----------
__global__ void final_k(const float* __restrict__ hlast, const float* __restrict__ score_acc,
                        const float* __restrict__ dyw, const float* __restrict__ dyb,
                        const float* __restrict__ scoreb, float* __restrict__ out) {
    int row = blockIdx.x, lane = threadIdx.x;
    int n = row % 96, k = row / 96;
    __shared__ float sh_h[48];
    if (lane < 48) sh_h[lane] = hlast[row * 48 + lane];
    __syncthreads();
    if (lane < 80) {
        float a = dyb[lane];
#pragma unroll 8
        for (int d = 0; d < 48; d++) a += sh_h[d] * dyw[lane * 48 + d];
        a = fmaxf(a, 0.0f);
        int j = lane / 40, tt = lane % 40;
        out[((k * TT + tt) * NN + n) * 2 + j] = a;
    } else if (lane == 80) {
        out[76800 + row] = score_acc[row] + 40.0f * scoreb[0];
    }
}

extern "C" void kernel_launch(void* const* d_in, const int* in_sizes, int n_in,
                              void* d_out, int out_size, void* d_ws, size_t ws_size,
                              hipStream_t stream) {
    const float* hx  = (const float*)d_in[0];
    const float* cur = (const float*)d_in[1];
    const float* yp  = (const float*)d_in[2];
    const float* img = (const float*)d_in[3];
    const float* c1w = (const float*)d_in[4];
    const float* c1b = (const float*)d_in[5];
    const float* c2w = (const float*)d_in[6];
    const float* c2b = (const float*)d_in[7];
    const float* vw  = (const float*)d_in[8];
    const float* vb  = (const float*)d_in[9];
    const float* wih = (const float*)d_in[10];
    const float* whh = (const float*)d_in[11];
    const float* bih = (const float*)d_in[12];
    const float* bhh = (const float*)d_in[13];
    const float* scfw = (const float*)d_in[14];
    const float* scfb = (const float*)d_in[15];
    const float* scw  = (const float*)d_in[16];
    const float* scb  = (const float*)d_in[17];
    const float* dyw  = (const float*)d_in[18];
    const float* dyb  = (const float*)d_in[19];
    float* out = (float*)d_out;

    char* ws = (char*)d_ws;
    // lifetimes: fmap1/fmap dead before recur_k; h0hist/flags alias that region.
    float* fmap1 = (float*)(ws + 0);               // [0, 409600)  dead after conv2
    float* h0hist = (float*)(ws + 0);              // [0, 755712)  recur_k
    int*   flags  = (int*)(ws + 755712);           // [755712, 768000)  96 x 128B
    int*   t_done = (int*)(ws + 768000);           // [768000, 768004)
    float* fmap  = (float*)(ws + 819200);          // [819200, 1638400) dead after lhalf_k
    float* lhalf = (float*)(ws + 1638400);         // -> 9011200
    signed char* win = (signed char*)(ws + 9011200);     // -> 10393600
    unsigned char* cnt = (unsigned char*)(ws + 10393600);// -> 11776000
    float* hfin = (float*)(ws + 11776000);         // -> 11960320
    float* score_acc = (float*)(ws + 11960320);    // -> 11964160
    float* wt_scf = (float*)(ws + 11964160);       // -> 12295936
    float* wih_lt = (float*)(ws + 12295936);       // -> 12323584
    float* wih_rt = (float*)(ws + 12323584);       // -> 12351232
    float* whh_t  = (float*)(ws + 12351232);       // -> 12378880

    hipMemsetAsync(flags, 0, 12292, stream);  // flags + t_done

    conv1_k<<<400, 256, 0, stream>>>(img, c1w, c1b, fmap1);
    conv2_k<<<800, 256, 0, stream>>>(fmap1, c2w, c2b, fmap);
    prep_w<<<(36 * 48 * 48 + 48 * 144 + 255) / 256, 256, 0, stream>>>(scfw, wih, whh, wt_scf,
                                                                      wih_lt, wih_rt, whh_t);
    lhalf_k<<<TT * KK * NN, 64, 0, stream>>>(yp, cur, fmap, vw, vb, lhalf);
    bins2_k<<<TT * KK, 256, 0, stream>>>(yp, win, cnt);

    recur_k<<<960, 64, 0, stream>>>(hx, h0hist, lhalf, win, cnt, wt_scf, wih_lt, wih_rt,
                                    whh_t, bih, bhh, scfb, scw, score_acc, hfin, flags, t_done);
    final_k<<<960, 128, 0, stream>>>(hfin, score_acc, dyw, dyb, scb, out);
}